// Round 10
// baseline (72.989 us; speedup 1.0000x reference)
//
#include <hip/hip_runtime.h>
#include <math.h>

#define HWP 3136   // 56*56
#define W56 56

// ---- one-shot weight pre-quantization into d_ws ----
__global__ __launch_bounds__(256) void quant_weights(const float* __restrict__ wgt,
                                                     float* __restrict__ wq, int n) {
    int i = blockIdx.x * 256 + threadIdx.x;
    if (i < n) {
        float v  = wgt[i];
        float s  = (v > 0.f) ? 1.f : ((v < 0.f) ? -1.f : 0.f);
        float sh = rintf(log2f(fabsf(v) + 1e-45f));   // round-half-even = jnp.round
        sh = fminf(fmaxf(sh, -14.f), 0.f);
        wq[i] = s * exp2f(sh);
    }
}

__device__ __forceinline__ void quant9(float* w) {
    #pragma unroll
    for (int k = 0; k < 9; ++k) {
        float v  = w[k];
        float s  = (v > 0.f) ? 1.f : ((v < 0.f) ? -1.f : 0.f);
        float sh = rintf(log2f(fabsf(v) + 1e-45f));
        sh = fminf(fmaxf(sh, -14.f), 0.f);
        w[k] = s * exp2f(sh);
    }
}

// round_to_fixed: floor to 2^-16 grid (clip to +/-2^15 is a no-op for N(0,1) data)
__device__ __forceinline__ float qfix(float v) {
    return floorf(v * 65536.f) * (1.f / 65536.f);
}

// DPP within 16-lane rows. ISA semantics (GCN/CDNA):
//   row_shr:1 (0x111): lane i reads lane i-1  -> use for LEFT  halo (lane 0 -> 0)
//   row_shl:1 (0x101): lane i reads lane i+1  -> use for RIGHT halo (lane15 -> 0)
__device__ __forceinline__ float dpp_from_left(float v) {    // lane n <- lane n-1
    return __int_as_float(__builtin_amdgcn_update_dpp(
        0, __float_as_int(v), 0x111, 0xF, 0xF, true));       // row_shr:1
}
__device__ __forceinline__ float dpp_from_right(float v) {   // lane n <- lane n+1
    return __int_as_float(__builtin_amdgcn_update_dpp(
        0, __float_as_int(v), 0x101, 0xF, 0xF, true));       // row_shl:1
}

// LDS-free: one 16-lane group per 4-row x 56-col output strip. Lane w4 owns a
// 4x4 patch (w4<14 active). Six f4 row-loads straight from global (L1/L2-hot,
// plane = 12.5 KB), halo columns via DPP from neighbor lanes. No barriers.
__global__ __launch_bounds__(256) void dwconv3x3_dpp(
    const float* __restrict__ x, const float* __restrict__ wq,
    float* __restrict__ out, int C, int nTasks, int preq)
{
    const int gtid = blockIdx.x * 256 + threadIdx.x;
    const int task = gtid >> 4;           // patch-row strip id: plane*14 + hp
    const int w4   = gtid & 15;
    if (task >= nTasks) return;

    const int plane = task / 14;
    const int hp    = task - plane * 14;
    const int h0    = hp * 4;
    const int wc    = w4 * 4;

    const float* __restrict__ xp = x + (size_t)plane * HWP;

    float w[9];
    {
        const float* wp = wq + (size_t)(plane % C) * 9;
        #pragma unroll
        for (int k = 0; k < 9; ++k) w[k] = wp[k];
        if (!preq) quant9(w);
    }
    const float w00 = w[0], w01 = w[1], w02 = w[2];
    const float w10 = w[3], w11 = w[4], w12 = w[5];
    const float w20 = w[6], w21 = w[7], w22 = w[8];

    float4 o0 = make_float4(0.f, 0.f, 0.f, 0.f);
    float4 o1 = o0, o2 = o0, o3 = o0;

    #pragma unroll
    for (int r = 0; r < 6; ++r) {
        const int row = h0 + r - 1;                 // input row for this pass
        float4 q = make_float4(0.f, 0.f, 0.f, 0.f);
        if (w4 < 14 && row >= 0 && row < 56)        // vertical halo -> zeros
            q = *(const float4*)(xp + row * W56 + wc);
        q.x = qfix(q.x); q.y = qfix(q.y); q.z = qfix(q.z); q.w = qfix(q.w);

        float lv = dpp_from_left(q.w);              // col wc-1 (0 at w4==0: halo)
        float rv = dpp_from_right(q.x);             // col wc+4
        if (w4 == 13) rv = 0.f;                     // right image halo (lane14 q=0 anyway)

        #define APPLY(o, a, b, c)                                      \
            o.x = fmaf(a, lv,  fmaf(b, q.x, fmaf(c, q.y, o.x)));       \
            o.y = fmaf(a, q.x, fmaf(b, q.y, fmaf(c, q.z, o.y)));       \
            o.z = fmaf(a, q.y, fmaf(b, q.z, fmaf(c, q.w, o.z)));       \
            o.w = fmaf(a, q.z, fmaf(b, q.w, fmaf(c, rv,  o.w)));
        // input row h0+r-1 feeds output p with weight row dh = r-p (0..2)
        if (r == 0)      { APPLY(o0, w00, w01, w02) }
        else if (r == 1) { APPLY(o1, w00, w01, w02) APPLY(o0, w10, w11, w12) }
        else if (r == 2) { APPLY(o2, w00, w01, w02) APPLY(o1, w10, w11, w12) APPLY(o0, w20, w21, w22) }
        else if (r == 3) { APPLY(o3, w00, w01, w02) APPLY(o2, w10, w11, w12) APPLY(o1, w20, w21, w22) }
        else if (r == 4) { APPLY(o3, w10, w11, w12) APPLY(o2, w20, w21, w22) }
        else             { APPLY(o3, w20, w21, w22) }
        #undef APPLY
    }

    if (w4 < 14) {
        float* __restrict__ op = out + (size_t)plane * HWP + h0 * W56 + wc;
        *(float4*)(op)           = o0;
        *(float4*)(op + W56)     = o1;
        *(float4*)(op + 2 * W56) = o2;
        *(float4*)(op + 3 * W56) = o3;
    }
}

extern "C" void kernel_launch(void* const* d_in, const int* in_sizes, int n_in,
                              void* d_out, int out_size, void* d_ws, size_t ws_size,
                              hipStream_t stream) {
    const float* x   = (const float*)d_in[0];
    const float* wgt = (const float*)d_in[1];
    float* out       = (float*)d_out;

    const int planes = out_size / HWP;    // B*C = 12288
    const int nW     = in_sizes[1];       // C*9 = 3456
    const int C      = nW / 9;

    int preq = (ws_size >= (size_t)nW * sizeof(float)) ? 1 : 0;
    const float* wqp = wgt;
    if (preq) {
        float* wqbuf = (float*)d_ws;
        quant_weights<<<(nW + 255) / 256, 256, 0, stream>>>(wgt, wqbuf, nW);
        wqp = wqbuf;
    }

    const int nTasks   = planes * 14;          // 4-row strips
    const int nThreads = nTasks * 16;
    dwconv3x3_dpp<<<(nThreads + 255) / 256, 256, 0, stream>>>(
        x, wqp, out, C, nTasks, preq);
}

// Round 12
// 58.444 us; speedup vs baseline: 1.2489x; 1.2489x over previous
//
#include <hip/hip_runtime.h>
#include <math.h>

#define HWP 3136   // 56*56
#define W56 56

typedef float v4f __attribute__((ext_vector_type(4)));   // native vec: OK for nontemporal builtins

// ---- one-shot weight pre-quantization into d_ws ----
__global__ __launch_bounds__(256) void quant_weights(const float* __restrict__ wgt,
                                                     float* __restrict__ wq, int n) {
    int i = blockIdx.x * 256 + threadIdx.x;
    if (i < n) {
        float v  = wgt[i];
        float s  = (v > 0.f) ? 1.f : ((v < 0.f) ? -1.f : 0.f);
        float sh = rintf(log2f(fabsf(v) + 1e-45f));   // round-half-even = jnp.round
        sh = fminf(fmaxf(sh, -14.f), 0.f);
        wq[i] = s * exp2f(sh);
    }
}

__device__ __forceinline__ float quantw(float v) {
    float s  = (v > 0.f) ? 1.f : ((v < 0.f) ? -1.f : 0.f);
    float sh = rintf(log2f(fabsf(v) + 1e-45f));
    sh = fminf(fmaxf(sh, -14.f), 0.f);
    return s * exp2f(sh);
}

// round_to_fixed: floor to 2^-16 grid (clip to +/-2^15 is a no-op for N(0,1) data)
__device__ __forceinline__ float qfix(float v) {
    return floorf(v * 65536.f) * (1.f / 65536.f);
}

// DPP within 16-lane rows (verified R10):
//   row_shr:1 (0x111): lane i <- lane i-1  (LEFT halo; lane 0 -> 0 via bound_ctrl)
//   row_shl:1 (0x101): lane i <- lane i+1  (RIGHT halo; disabled/oob lane -> 0)
__device__ __forceinline__ float dpp_from_left(float v) {
    return __int_as_float(__builtin_amdgcn_update_dpp(
        0, __float_as_int(v), 0x111, 0xF, 0xF, true));
}
__device__ __forceinline__ float dpp_from_right(float v) {
    return __int_as_float(__builtin_amdgcn_update_dpp(
        0, __float_as_int(v), 0x101, 0xF, 0xF, true));
}

__device__ __forceinline__ float4 ldrow(const float* __restrict__ xp,
                                        int row, int wc, int w4) {
    float4 q = make_float4(0.f, 0.f, 0.f, 0.f);
    if (w4 < 14 && row >= 0 && row < 56)
        q = *(const float4*)(xp + row * W56 + wc);
    return q;
}

__device__ __forceinline__ void nt_store4(float* p, const float4& v) {
    v4f t; t.x = v.x; t.y = v.y; t.z = v.z; t.w = v.w;
    __builtin_nontemporal_store(t, (v4f*)p);
}

// Strip = (plane, hp): 4 output rows x 56 cols, handled by one 16-lane group
// (lane w4 owns 4 cols; w4<14 active). Each block walks 6 strips with a
// two-set register ping-pong: prefetch set B (6 rows + 9 weights) while
// computing set A. No LDS, no barriers. Output via non-temporal stores so the
// 154 MB input stays L3-resident.
__global__ __launch_bounds__(256) void dwconv3x3_pipe_dpp(
    const float* __restrict__ x, const float* __restrict__ wq,
    float* __restrict__ out, int C, int nStrips, int stepStrips, int nPairs,
    int preq)
{
    const int tid = threadIdx.x;
    const int g   = tid >> 4;
    const int w4  = tid & 15;
    const int wc  = w4 * 4;

    const float4 z4 = make_float4(0.f, 0.f, 0.f, 0.f);
    float4 Aq0=z4,Aq1=z4,Aq2=z4,Aq3=z4,Aq4=z4,Aq5=z4;
    float4 Bq0=z4,Bq1=z4,Bq2=z4,Bq3=z4,Bq4=z4,Bq5=z4;
    float Ak0=0,Ak1=0,Ak2=0,Ak3=0,Ak4=0,Ak5=0,Ak6=0,Ak7=0,Ak8=0;
    float Bk0=0,Bk1=0,Bk2=0,Bk3=0,Bk4=0,Bk5=0,Bk6=0,Bk7=0,Bk8=0;
    int As = nStrips, Bs = nStrips;

    #define LOADSET(P, sv) {                                                 \
        P##s = (sv);                                                         \
        if (P##s < nStrips) {                                                \
            int pl = P##s / 14; int hp = P##s - pl * 14; int h0 = hp * 4;    \
            const float* __restrict__ xp = x + (size_t)pl * HWP;             \
            P##q0 = ldrow(xp, h0 - 1, wc, w4);                               \
            P##q1 = ldrow(xp, h0 + 0, wc, w4);                               \
            P##q2 = ldrow(xp, h0 + 1, wc, w4);                               \
            P##q3 = ldrow(xp, h0 + 2, wc, w4);                               \
            P##q4 = ldrow(xp, h0 + 3, wc, w4);                               \
            P##q5 = ldrow(xp, h0 + 4, wc, w4);                               \
            const float* wp = wq + (size_t)(pl % C) * 9;                     \
            P##k0 = wp[0]; P##k1 = wp[1]; P##k2 = wp[2];                     \
            P##k3 = wp[3]; P##k4 = wp[4]; P##k5 = wp[5];                     \
            P##k6 = wp[6]; P##k7 = wp[7]; P##k8 = wp[8];                     \
            if (!preq) {                                                     \
                P##k0 = quantw(P##k0); P##k1 = quantw(P##k1);                \
                P##k2 = quantw(P##k2); P##k3 = quantw(P##k3);                \
                P##k4 = quantw(P##k4); P##k5 = quantw(P##k5);                \
                P##k6 = quantw(P##k6); P##k7 = quantw(P##k7);                \
                P##k8 = quantw(P##k8);                                       \
            }                                                                \
        }                                                                    \
    }

    #define APPLY(o, a, b, c)                                      \
        o.x = fmaf(a, lv,  fmaf(b, q.x, fmaf(c, q.y, o.x)));       \
        o.y = fmaf(a, q.x, fmaf(b, q.y, fmaf(c, q.z, o.y)));       \
        o.z = fmaf(a, q.y, fmaf(b, q.z, fmaf(c, q.w, o.z)));       \
        o.w = fmaf(a, q.z, fmaf(b, q.w, fmaf(c, rv,  o.w)));
    #define ROWQ(P, n) float4 q = P##q##n;                                   \
        q.x = qfix(q.x); q.y = qfix(q.y); q.z = qfix(q.z); q.w = qfix(q.w);  \
        float lv = dpp_from_left(q.w);                                       \
        float rv = dpp_from_right(q.x);                                      \
        if (w4 == 13) rv = 0.f;

    #define COMPUTE(P) if (P##s < nStrips && w4 < 14) {                      \
        int pl = P##s / 14; int hp = P##s - pl * 14; int h0 = hp * 4;        \
        float4 o0 = z4, o1 = z4, o2 = z4, o3 = z4;                           \
        { ROWQ(P,0) APPLY(o0, P##k0, P##k1, P##k2) }                         \
        { ROWQ(P,1) APPLY(o1, P##k0, P##k1, P##k2)                           \
                    APPLY(o0, P##k3, P##k4, P##k5) }                         \
        { ROWQ(P,2) APPLY(o2, P##k0, P##k1, P##k2)                           \
                    APPLY(o1, P##k3, P##k4, P##k5)                           \
                    APPLY(o0, P##k6, P##k7, P##k8) }                         \
        { ROWQ(P,3) APPLY(o3, P##k0, P##k1, P##k2)                           \
                    APPLY(o2, P##k3, P##k4, P##k5)                           \
                    APPLY(o1, P##k6, P##k7, P##k8) }                         \
        { ROWQ(P,4) APPLY(o3, P##k3, P##k4, P##k5)                           \
                    APPLY(o2, P##k6, P##k7, P##k8) }                         \
        { ROWQ(P,5) APPLY(o3, P##k6, P##k7, P##k8) }                         \
        float* op = out + (size_t)pl * HWP + h0 * W56 + wc;                  \
        nt_store4(op,            o0);                                        \
        nt_store4(op + W56,      o1);                                        \
        nt_store4(op + 2 * W56,  o2);                                        \
        nt_store4(op + 3 * W56,  o3);                                        \
    }

    // ping-pong over this block's strips: s, s+step, s+2*step, ...
    LOADSET(A, blockIdx.x * 16 + g);
    for (int ii = 0; ii < nPairs; ++ii) {
        LOADSET(B, As + stepStrips);     // prefetch while computing A
        COMPUTE(A)
        LOADSET(A, Bs + stepStrips);     // prefetch while computing B
        COMPUTE(B)
    }

    #undef LOADSET
    #undef APPLY
    #undef ROWQ
    #undef COMPUTE
}

extern "C" void kernel_launch(void* const* d_in, const int* in_sizes, int n_in,
                              void* d_out, int out_size, void* d_ws, size_t ws_size,
                              hipStream_t stream) {
    const float* x   = (const float*)d_in[0];
    const float* wgt = (const float*)d_in[1];
    float* out       = (float*)d_out;

    const int planes = out_size / HWP;    // B*C = 12288
    const int nW     = in_sizes[1];       // C*9 = 3456
    const int C      = nW / 9;

    int preq = (ws_size >= (size_t)nW * sizeof(float)) ? 1 : 0;
    const float* wqp = wgt;
    if (preq) {
        float* wqbuf = (float*)d_ws;
        quant_weights<<<(nW + 255) / 256, 256, 0, stream>>>(wgt, wqbuf, nW);
        wqp = wqbuf;
    }

    const int nStrips    = planes * 14;          // 172032
    const int gridsz     = 1792;                 // 6 strips/block exactly at this shape
    const int stepStrips = gridsz * 16;          // 28672
    const int iters      = (nStrips + stepStrips - 1) / stepStrips;   // 6
    const int nPairs     = (iters + 1) / 2;                           // 3

    dwconv3x3_pipe_dpp<<<gridsz, 256, 0, stream>>>(
        x, wqp, out, C, nStrips, stepStrips, nPairs, preq);
}